// Round 2
// baseline (33119.308 us; speedup 1.0000x reference)
//
#include <hip/hip_runtime.h>
#include <hip/hip_bf16.h>

// FNO2d: B=16, CIN=20, H=W=256, WIDTH=64, M1=M2=16, NLAYERS=4, FC_HID=128, COUT=20
// Round 1: same truncated-DFT algorithm as R0, but (a) projection fc1+gelu+fc2 fused
// into one kernel (no mid buffer), (b) batch-chunked with chunk size chosen from
// ws_size so we never overrun the workspace (R0 used 403MB unconditionally -- the
// likely cause of the harness crash).
//
// Per-sample workspace (floats):
//   h  : 64*65536      = 4,194,304
//   T/G: 64*256*16*2   =   524,288   (T2 for fwd stage-1, reused as G2 for inv stage-1)
//   X2 : 64*32*16*2    =    65,536
//   Y2 : 64*32*16*2    =    65,536
//   total 4,849,664 floats = 19.4 MB per sample; CB=16 -> 310 MB.

#define HW_TOT 65536
#define PI2_256 0.024543692606170259758f  // 2*pi/256

__device__ __forceinline__ float gelu_exact(float v) {
    return 0.5f * v * (1.0f + erff(v * 0.70710678118654752440f));
}

// ---------------- 1x1 conv (lift): out[b,o,p] = sum_ci w[o,ci]*in[b,ci,p] + bias[o]
template<int CI, int CO, int WS>
__global__ void __launch_bounds__(256) conv1x1_kernel(
    const float* __restrict__ in, const float* __restrict__ w,
    const float* __restrict__ bias, float* __restrict__ out)
{
    const int b = blockIdx.y;
    const int p = blockIdx.x * 256 + threadIdx.x;
    const float* inp = in + (size_t)b * CI * HW_TOT + p;
    float acc[CO];
#pragma unroll
    for (int o = 0; o < CO; ++o) acc[o] = bias[o];
    for (int ci = 0; ci < CI; ++ci) {
        float hv = inp[(size_t)ci * HW_TOT];
#pragma unroll
        for (int o = 0; o < CO; ++o)
            acc[o] = fmaf(w[o * WS + ci], hv, acc[o]);
    }
    float* op = out + (size_t)b * CO * HW_TOT + p;
#pragma unroll
    for (int o = 0; o < CO; ++o) op[(size_t)o * HW_TOT] = acc[o];
}

// ---------------- forward DFT over y: T[row,ky] = sum_y h[row,y] * e^{-2pi i ky y/256}, ky<16
// row = (b,c,x) flattened (chunk-local). Block: 8 rows; 256 thr = 8 rows x 16 ky x 2 comps.
__global__ void __launch_bounds__(256) dft1_kernel(
    const float* __restrict__ h, float* __restrict__ T)
{
    __shared__ float rows[8][256];
    __shared__ float trig[512];   // [0..255]=cos(2pi m/256), [256..511]=-sin
    const int t = threadIdx.x;
    {
        float a = (float)t * PI2_256;
        trig[t]       = cosf(a);
        trig[256 + t] = -sinf(a);
    }
    const size_t base = (size_t)blockIdx.x * 2048;
    for (int i = t; i < 2048; i += 256) rows[i >> 8][i & 255] = h[base + i];
    __syncthreads();

    const int lr = t >> 5, ky = (t >> 1) & 15, comp = t & 1;
    const float* tg = &trig[comp << 8];
    float acc = 0.0f;
    int m = 0;
    for (int y = 0; y < 256; ++y) {
        acc = fmaf(rows[lr][y], tg[m], acc);
        m = (m + ky) & 255;
    }
    const size_t row = (size_t)blockIdx.x * 8 + lr;
    T[row * 32 + ky * 2 + comp] = acc;
}

// ---------------- forward DFT over x: X[bc,kxi,ky] = sum_x T[bc,x,ky] * e^{-2pi i kx x/256}
// kxi in 0..31, kx = kxi<16 ? kxi : 224+kxi (i.e. 240..255)
__global__ void __launch_bounds__(512) dft2_kernel(
    const float2* __restrict__ T2, float2* __restrict__ X2)
{
    __shared__ float cs[256], sn[256];
    const int t = threadIdx.x;
    if (t < 256) {
        float a = (float)t * PI2_256;
        cs[t] = cosf(a); sn[t] = sinf(a);
    }
    __syncthreads();
    const int bc = blockIdx.x;          // chunk-local b*64 + c
    const int ky = t & 15, kxi = t >> 4;
    const int kx = (kxi < 16) ? kxi : (224 + kxi);
    const float2* Tp = T2 + (size_t)bc * 4096 + ky;
    float xr = 0.0f, xi = 0.0f;
    int m = 0;
    for (int x = 0; x < 256; ++x) {
        float2 tv = Tp[(size_t)x * 16];
        float c = cs[m], s = sn[m];
        xr = fmaf(tv.x, c, fmaf(tv.y, s, xr));      // (Tr+iTi)(c - i s)
        xi = fmaf(tv.y, c, fmaf(-tv.x, s, xi));
        m = (m + kx) & 255;
    }
    X2[(size_t)bc * 512 + t] = make_float2(xr, xi);
}

// ---------------- complex mode mixing: Y[b,o,kxi,ky] = sum_i X[b,i,kxi,ky] * W[i,o,kxm,ky]
__global__ void __launch_bounds__(512) mix_kernel(
    const float2* __restrict__ X2, float2* __restrict__ Y2,
    const float* __restrict__ w1r, const float* __restrict__ w1i,
    const float* __restrict__ w2r, const float* __restrict__ w2i, int layer)
{
    const int bo = blockIdx.x;
    const int b = bo >> 6, o = bo & 63;
    const int t = threadIdx.x;
    const int ky = t & 15, kxi = t >> 4;
    const bool top = (kxi < 16);
    const int kxm = top ? kxi : (kxi - 16);
    const float* wr = top ? w1r : w2r;
    const float* wi = top ? w1i : w2i;
    float yr = 0.0f, yi = 0.0f;
    for (int i = 0; i < 64; ++i) {
        float2 xv = X2[((size_t)(b * 64 + i) * 32 + kxi) * 16 + ky];
        size_t widx = (((size_t)layer * 64 + i) * 64 + o) * 256 + (kxm * 16 + ky);
        float wrv = wr[widx], wiv = wi[widx];
        yr = fmaf(xv.x, wrv, fmaf(-xv.y, wiv, yr));
        yi = fmaf(xv.x, wiv, fmaf(xv.y, wrv, yi));
    }
    Y2[((size_t)(b * 64 + o) * 32 + kxi) * 16 + ky] = make_float2(yr, yi);
}

// ---------------- inverse DFT over x: G[bo,x,ky] = sum_kxi Y[bo,kxi,ky] * e^{+2pi i kx x/256}
__global__ void __launch_bounds__(256) idft1_kernel(
    const float2* __restrict__ Y2, float2* __restrict__ G2)
{
    __shared__ float cs[256], sn[256];
    const int t = threadIdx.x;
    {
        float a = (float)t * PI2_256;
        cs[t] = cosf(a); sn[t] = sinf(a);
    }
    __syncthreads();
    const int bo = blockIdx.x >> 4;     // chunk-local b*64 + o
    const int xc = blockIdx.x & 15;
    const int ky = t & 15, xo = t >> 4;
    const int x = xc * 16 + xo;
    const float2* Yp = Y2 + (size_t)bo * 512 + ky;
    float gr = 0.0f, gi = 0.0f;
    for (int kxi = 0; kxi < 32; ++kxi) {
        float2 yv = Yp[(size_t)kxi * 16];
        int kx = (kxi < 16) ? kxi : (224 + kxi);
        int m = (kx * x) & 255;
        float c = cs[m], s = sn[m];
        gr = fmaf(yv.x, c, fmaf(-yv.y, s, gr));     // (Yr+iYi)(c + i s)
        gi = fmaf(yv.x, s, fmaf(yv.y, c, gi));
    }
    G2[((size_t)bo * 256 + x) * 16 + ky] = make_float2(gr, gi);
}

// ---------------- fused: pointwise conv + inverse DFT over y (Re, Hermitian-doubled)
// + add + GELU, IN PLACE on h. Block = (b, x-row); thread t owns column y=t.
__global__ void __launch_bounds__(256) pwcomb_kernel(
    float* __restrict__ h, const float2* __restrict__ G2,
    const float* __restrict__ pw_w, const float* __restrict__ pw_b,
    int layer, int do_gelu)
{
    __shared__ float2 Gl[64 * 16];
    __shared__ float cs[256], sn[256];
    const int t = threadIdx.x;
    {
        float a = (float)t * PI2_256;
        cs[t] = cosf(a); sn[t] = sinf(a);
    }
    const int b = blockIdx.x >> 8;
    const int x = blockIdx.x & 255;
    for (int idx = t; idx < 1024; idx += 256) {
        int o = idx >> 4, ky = idx & 15;
        Gl[idx] = G2[((size_t)(b * 64 + o) * 256 + x) * 16 + ky];
    }
    __syncthreads();

    const int y = t;
    const size_t hbase = (size_t)b * 64 * HW_TOT + (size_t)x * 256 + y;
    const float* wl = pw_w + layer * 64 * 64;
    const float* bl = pw_b + layer * 64;

    float acc[64];
#pragma unroll
    for (int o = 0; o < 64; ++o) acc[o] = bl[o];
    for (int ci = 0; ci < 64; ++ci) {
        float hv = h[hbase + (size_t)ci * HW_TOT];
#pragma unroll
        for (int o = 0; o < 64; ++o)
            acc[o] = fmaf(wl[o * 64 + ci], hv, acc[o]);
    }

    // spectral part: x1 = (1/65536) * sum_ky c_ky * (Gr*cos - Gi*sin), theta = 2pi ky y/256
    const float inv = 1.0f / 65536.0f;
    float csv[16], snv[16];
#pragma unroll
    for (int ky = 0; ky < 16; ++ky) {
        int m = (ky * y) & 255;
        float wk = (ky == 0) ? inv : 2.0f * inv;
        csv[ky] = wk * cs[m];
        snv[ky] = wk * sn[m];
    }
#pragma unroll
    for (int o = 0; o < 64; ++o) {
        float s = 0.0f;
#pragma unroll
        for (int ky = 0; ky < 16; ++ky) {
            float2 g = Gl[o * 16 + ky];
            s = fmaf(csv[ky], g.x, fmaf(-snv[ky], g.y, s));
        }
        acc[o] += s;
    }

#pragma unroll
    for (int o = 0; o < 64; ++o) {
        float v = acc[o];
        if (do_gelu) v = gelu_exact(v);
        h[hbase + (size_t)o * HW_TOT] = v;
    }
}

// ---------------- fused projection: out = fc2(gelu(fc1(h))) per pixel, no mid buffer.
__global__ void __launch_bounds__(256) proj_kernel(
    const float* __restrict__ h,
    const float* __restrict__ w1, const float* __restrict__ b1,
    const float* __restrict__ w2, const float* __restrict__ b2,
    float* __restrict__ out)
{
    const int b = blockIdx.y;
    const int p = blockIdx.x * 256 + threadIdx.x;
    const float* hp = h + (size_t)b * 64 * HW_TOT + p;
    float hreg[64];
#pragma unroll
    for (int ci = 0; ci < 64; ++ci) hreg[ci] = hp[(size_t)ci * HW_TOT];
    float acc[20];
#pragma unroll
    for (int o = 0; o < 20; ++o) acc[o] = b2[o];
    for (int hd = 0; hd < 128; ++hd) {
        float v = b1[hd];
        const float* wr = w1 + hd * 64;
#pragma unroll
        for (int ci = 0; ci < 64; ++ci) v = fmaf(wr[ci], hreg[ci], v);
        v = gelu_exact(v);
#pragma unroll
        for (int o = 0; o < 20; ++o) acc[o] = fmaf(w2[o * 128 + hd], v, acc[o]);
    }
    float* op = out + (size_t)b * 20 * HW_TOT + p;
#pragma unroll
    for (int o = 0; o < 20; ++o) op[(size_t)o * HW_TOT] = acc[o];
}

extern "C" void kernel_launch(void* const* d_in, const int* in_sizes, int n_in,
                              void* d_out, int out_size, void* d_ws, size_t ws_size,
                              hipStream_t stream)
{
    const float* x     = (const float*)d_in[0];
    const float* w1r   = (const float*)d_in[1];
    const float* w1i   = (const float*)d_in[2];
    const float* w2r   = (const float*)d_in[3];
    const float* w2i   = (const float*)d_in[4];
    const float* pw_w  = (const float*)d_in[5];
    const float* pw_b  = (const float*)d_in[6];
    const float* fc0_w = (const float*)d_in[7];
    const float* fc0_b = (const float*)d_in[8];
    const float* fc1_w = (const float*)d_in[9];
    const float* fc1_b = (const float*)d_in[10];
    const float* fc2_w = (const float*)d_in[11];
    const float* fc2_b = (const float*)d_in[12];
    float* out = (float*)d_out;
    float* ws  = (float*)d_ws;

    // pick largest batch chunk CB that fits ws_size (19.4 MB per sample)
    const size_t per_sample_floats = 4849664;   // 4,194,304 + 524,288 + 65,536 + 65,536
    int CB = 16;
    while (CB > 1 && (size_t)CB * per_sample_floats * 4 > ws_size) CB >>= 1;

    float*  h  = ws;
    float*  T  = ws + (size_t)CB * 4194304;
    float2* T2 = (float2*)T;
    float2* X2 = (float2*)(T + (size_t)CB * 524288);
    float2* Y2 = (float2*)(T + (size_t)CB * 524288 + (size_t)CB * 65536);
    float2* G2 = T2;   // reuse: T dead once X2 produced; G written after mix

    for (int c0 = 0; c0 < 16; c0 += CB) {
        const float* xc = x + (size_t)c0 * 20 * HW_TOT;
        float* oc = out + (size_t)c0 * 20 * HW_TOT;

        // lift: (CB,20,HW) -> h (CB,64,HW)
        conv1x1_kernel<20, 64, 20>
            <<<dim3(256, CB), 256, 0, stream>>>(xc, fc0_w, fc0_b, h);

        for (int l = 0; l < 4; ++l) {
            dft1_kernel <<<CB * 64 * 256 / 8, 256, 0, stream>>>(h, T);
            dft2_kernel <<<CB * 64, 512, 0, stream>>>(T2, X2);
            mix_kernel  <<<CB * 64, 512, 0, stream>>>(X2, Y2, w1r, w1i, w2r, w2i, l);
            idft1_kernel<<<CB * 64 * 16, 256, 0, stream>>>(Y2, G2);
            pwcomb_kernel<<<CB * 256, 256, 0, stream>>>(h, G2, pw_w, pw_b, l, (l < 3) ? 1 : 0);
        }

        proj_kernel<<<dim3(256, CB), 256, 0, stream>>>(h, fc1_w, fc1_b, fc2_w, fc2_b, oc);
    }
}

// Round 3
// 4400.089 us; speedup vs baseline: 7.5270x; 7.5270x over previous
//
#include <hip/hip_runtime.h>
#include <hip/hip_bf16.h>

// FNO2d: B=16, CIN=20, H=W=256, WIDTH=64, M1=M2=16, NLAYERS=4, FC_HID=128, COUT=20
// Round 2: R1 profile showed pwcomb = 30.5/33.1 ms with VGPR=256 (spill cap),
// VALUBusy=1.7%, hbm_bytes=11GB/dispatch (20x amplification -> scratch spill
// traffic from acc[64]/thread). Rewrite pwcomb as LDS-tiled: 1024 threads/block,
// h-slice (64KB) + W tile (16KB) + G (8KB) staged in LDS, 16 acc/thread.
//
// Per-sample workspace (floats):
//   h  : 64*65536      = 4,194,304
//   T/G: 64*256*16*2   =   524,288   (T2 fwd stage-1, reused as G2 inv stage-1)
//   X2 : 64*32*16*2    =    65,536
//   Y2 : 64*32*16*2    =    65,536
//   total 4,849,664 floats = 19.4 MB per sample; CB=16 -> 310 MB.

#define HW_TOT 65536
#define PI2_256 0.024543692606170259758f  // 2*pi/256

__device__ __forceinline__ float gelu_exact(float v) {
    return 0.5f * v * (1.0f + erff(v * 0.70710678118654752440f));
}

// ---------------- 1x1 conv (lift): out[b,o,p] = sum_ci w[o,ci]*in[b,ci,p] + bias[o]
template<int CI, int CO, int WS>
__global__ void __launch_bounds__(256) conv1x1_kernel(
    const float* __restrict__ in, const float* __restrict__ w,
    const float* __restrict__ bias, float* __restrict__ out)
{
    const int b = blockIdx.y;
    const int p = blockIdx.x * 256 + threadIdx.x;
    const float* inp = in + (size_t)b * CI * HW_TOT + p;
    float acc[CO];
#pragma unroll
    for (int o = 0; o < CO; ++o) acc[o] = bias[o];
    for (int ci = 0; ci < CI; ++ci) {
        float hv = inp[(size_t)ci * HW_TOT];
#pragma unroll
        for (int o = 0; o < CO; ++o)
            acc[o] = fmaf(w[o * WS + ci], hv, acc[o]);
    }
    float* op = out + (size_t)b * CO * HW_TOT + p;
#pragma unroll
    for (int o = 0; o < CO; ++o) op[(size_t)o * HW_TOT] = acc[o];
}

// ---------------- forward DFT over y: T[row,ky] = sum_y h[row,y] * e^{-2pi i ky y/256}, ky<16
// row = (b,c,x) flattened (chunk-local). Block: 8 rows; 256 thr = 8 rows x 16 ky x 2 comps.
__global__ void __launch_bounds__(256) dft1_kernel(
    const float* __restrict__ h, float* __restrict__ T)
{
    __shared__ float rows[8][256];
    __shared__ float trig[512];   // [0..255]=cos(2pi m/256), [256..511]=-sin
    const int t = threadIdx.x;
    {
        float a = (float)t * PI2_256;
        trig[t]       = cosf(a);
        trig[256 + t] = -sinf(a);
    }
    const size_t base = (size_t)blockIdx.x * 2048;
    for (int i = t; i < 2048; i += 256) rows[i >> 8][i & 255] = h[base + i];
    __syncthreads();

    const int lr = t >> 5, ky = (t >> 1) & 15, comp = t & 1;
    const float* tg = &trig[comp << 8];
    float acc = 0.0f;
    int m = 0;
    for (int y = 0; y < 256; ++y) {
        acc = fmaf(rows[lr][y], tg[m], acc);
        m = (m + ky) & 255;
    }
    const size_t row = (size_t)blockIdx.x * 8 + lr;
    T[row * 32 + ky * 2 + comp] = acc;
}

// ---------------- forward DFT over x: X[bc,kxi,ky] = sum_x T[bc,x,ky] * e^{-2pi i kx x/256}
// kxi in 0..31, kx = kxi<16 ? kxi : 224+kxi (i.e. 240..255)
__global__ void __launch_bounds__(512) dft2_kernel(
    const float2* __restrict__ T2, float2* __restrict__ X2)
{
    __shared__ float cs[256], sn[256];
    const int t = threadIdx.x;
    if (t < 256) {
        float a = (float)t * PI2_256;
        cs[t] = cosf(a); sn[t] = sinf(a);
    }
    __syncthreads();
    const int bc = blockIdx.x;          // chunk-local b*64 + c
    const int ky = t & 15, kxi = t >> 4;
    const int kx = (kxi < 16) ? kxi : (224 + kxi);
    const float2* Tp = T2 + (size_t)bc * 4096 + ky;
    float xr = 0.0f, xi = 0.0f;
    int m = 0;
    for (int x = 0; x < 256; ++x) {
        float2 tv = Tp[(size_t)x * 16];
        float c = cs[m], s = sn[m];
        xr = fmaf(tv.x, c, fmaf(tv.y, s, xr));      // (Tr+iTi)(c - i s)
        xi = fmaf(tv.y, c, fmaf(-tv.x, s, xi));
        m = (m + kx) & 255;
    }
    X2[(size_t)bc * 512 + t] = make_float2(xr, xi);
}

// ---------------- complex mode mixing: Y[b,o,kxi,ky] = sum_i X[b,i,kxi,ky] * W[i,o,kxm,ky]
__global__ void __launch_bounds__(512) mix_kernel(
    const float2* __restrict__ X2, float2* __restrict__ Y2,
    const float* __restrict__ w1r, const float* __restrict__ w1i,
    const float* __restrict__ w2r, const float* __restrict__ w2i, int layer)
{
    const int bo = blockIdx.x;
    const int b = bo >> 6, o = bo & 63;
    const int t = threadIdx.x;
    const int ky = t & 15, kxi = t >> 4;
    const bool top = (kxi < 16);
    const int kxm = top ? kxi : (kxi - 16);
    const float* wr = top ? w1r : w2r;
    const float* wi = top ? w1i : w2i;
    float yr = 0.0f, yi = 0.0f;
    for (int i = 0; i < 64; ++i) {
        float2 xv = X2[((size_t)(b * 64 + i) * 32 + kxi) * 16 + ky];
        size_t widx = (((size_t)layer * 64 + i) * 64 + o) * 256 + (kxm * 16 + ky);
        float wrv = wr[widx], wiv = wi[widx];
        yr = fmaf(xv.x, wrv, fmaf(-xv.y, wiv, yr));
        yi = fmaf(xv.x, wiv, fmaf(xv.y, wrv, yi));
    }
    Y2[((size_t)(b * 64 + o) * 32 + kxi) * 16 + ky] = make_float2(yr, yi);
}

// ---------------- inverse DFT over x: G[bo,x,ky] = sum_kxi Y[bo,kxi,ky] * e^{+2pi i kx x/256}
__global__ void __launch_bounds__(256) idft1_kernel(
    const float2* __restrict__ Y2, float2* __restrict__ G2)
{
    __shared__ float cs[256], sn[256];
    const int t = threadIdx.x;
    {
        float a = (float)t * PI2_256;
        cs[t] = cosf(a); sn[t] = sinf(a);
    }
    __syncthreads();
    const int bo = blockIdx.x >> 4;     // chunk-local b*64 + o
    const int xc = blockIdx.x & 15;
    const int ky = t & 15, xo = t >> 4;
    const int x = xc * 16 + xo;
    const float2* Yp = Y2 + (size_t)bo * 512 + ky;
    float gr = 0.0f, gi = 0.0f;
    for (int kxi = 0; kxi < 32; ++kxi) {
        float2 yv = Yp[(size_t)kxi * 16];
        int kx = (kxi < 16) ? kxi : (224 + kxi);
        int m = (kx * x) & 255;
        float c = cs[m], s = sn[m];
        gr = fmaf(yv.x, c, fmaf(-yv.y, s, gr));     // (Yr+iYi)(c + i s)
        gi = fmaf(yv.x, s, fmaf(yv.y, c, gi));
    }
    G2[((size_t)bo * 256 + x) * 16 + ky] = make_float2(gr, gi);
}

// ---------------- fused: pointwise conv + inverse DFT over y (Re, Hermitian-doubled)
// + add + GELU, IN PLACE on h.
// Round-2 rewrite: 1024 threads/block, block = (b, x-row). LDS stages the full
// 64ci x 256y h-slice (64KB), the 64x64 W tile (16KB), G (8KB), trig (2KB) = 92KB.
// Thread = (y = t&255, og = t>>8): 16 accumulators (o = og*16 .. og*16+15).
// hs[ci][y]: 2-way bank alias (free). wls[o][ci]: wave-uniform broadcast (free).
__global__ void __launch_bounds__(1024) pwcomb_kernel(
    float* __restrict__ h, const float2* __restrict__ G2,
    const float* __restrict__ pw_w, const float* __restrict__ pw_b,
    int layer, int do_gelu)
{
    __shared__ float hs[64][256];       // 64 KB
    __shared__ float wls[64][64];       // 16 KB, [o][ci]
    __shared__ float2 Gl[64 * 16];      // 8 KB
    __shared__ float cs[256], sn[256];  // 2 KB
    const int t = threadIdx.x;
    if (t < 256) {
        float a = (float)t * PI2_256;
        cs[t] = cosf(a); sn[t] = sinf(a);
    }
    const int b = blockIdx.x >> 8;
    const int x = blockIdx.x & 255;

    // stage W layer tile (coalesced)
    const float* wl = pw_w + layer * 64 * 64;
    for (int i = t; i < 4096; i += 1024) ((float*)wls)[i] = wl[i];
    // stage G: exactly 1024 float2
    {
        int o = t >> 4, ky = t & 15;
        Gl[t] = G2[((size_t)(b * 64 + o) * 256 + x) * 16 + ky];
    }
    // stage h slice h[b, 0..63, x, 0..255] (coalesced; all reads before any write)
    const size_t hrow = (size_t)b * 64 * HW_TOT + (size_t)x * 256;
    for (int i = t; i < 16384; i += 1024)
        ((float*)hs)[i] = h[hrow + (size_t)(i >> 8) * HW_TOT + (i & 255)];
    __syncthreads();

    const int y = t & 255, og = t >> 8;     // og in 0..3
    const float* bl = pw_b + layer * 64;

    float acc[16];
#pragma unroll
    for (int o16 = 0; o16 < 16; ++o16) acc[o16] = bl[og * 16 + o16];
    for (int ci = 0; ci < 64; ++ci) {
        float hv = hs[ci][y];
#pragma unroll
        for (int o16 = 0; o16 < 16; ++o16)
            acc[o16] = fmaf(wls[og * 16 + o16][ci], hv, acc[o16]);
    }

    // spectral part: x1 = (1/65536) * sum_ky c_ky * (Gr*cos - Gi*sin), theta = 2pi ky y/256
    const float inv = 1.0f / 65536.0f;
    float csv[16], snv[16];
#pragma unroll
    for (int ky = 0; ky < 16; ++ky) {
        int m = (ky * y) & 255;
        float wk = (ky == 0) ? inv : 2.0f * inv;
        csv[ky] = wk * cs[m];
        snv[ky] = wk * sn[m];
    }
#pragma unroll
    for (int o16 = 0; o16 < 16; ++o16) {
        const int o = og * 16 + o16;
        float s = 0.0f;
#pragma unroll
        for (int ky = 0; ky < 16; ++ky) {
            float2 g = Gl[o * 16 + ky];
            s = fmaf(csv[ky], g.x, fmaf(-snv[ky], g.y, s));
        }
        float v = acc[o16] + s;
        if (do_gelu) v = gelu_exact(v);
        h[hrow + (size_t)o * HW_TOT + y] = v;
    }
}

// ---------------- fused projection: out = fc2(gelu(fc1(h))) per pixel, no mid buffer.
__global__ void __launch_bounds__(256) proj_kernel(
    const float* __restrict__ h,
    const float* __restrict__ w1, const float* __restrict__ b1,
    const float* __restrict__ w2, const float* __restrict__ b2,
    float* __restrict__ out)
{
    const int b = blockIdx.y;
    const int p = blockIdx.x * 256 + threadIdx.x;
    const float* hp = h + (size_t)b * 64 * HW_TOT + p;
    float hreg[64];
#pragma unroll
    for (int ci = 0; ci < 64; ++ci) hreg[ci] = hp[(size_t)ci * HW_TOT];
    float acc[20];
#pragma unroll
    for (int o = 0; o < 20; ++o) acc[o] = b2[o];
    for (int hd = 0; hd < 128; ++hd) {
        float v = b1[hd];
        const float* wr = w1 + hd * 64;
#pragma unroll
        for (int ci = 0; ci < 64; ++ci) v = fmaf(wr[ci], hreg[ci], v);
        v = gelu_exact(v);
#pragma unroll
        for (int o = 0; o < 20; ++o) acc[o] = fmaf(w2[o * 128 + hd], v, acc[o]);
    }
    float* op = out + (size_t)b * 20 * HW_TOT + p;
#pragma unroll
    for (int o = 0; o < 20; ++o) op[(size_t)o * HW_TOT] = acc[o];
}

extern "C" void kernel_launch(void* const* d_in, const int* in_sizes, int n_in,
                              void* d_out, int out_size, void* d_ws, size_t ws_size,
                              hipStream_t stream)
{
    const float* x     = (const float*)d_in[0];
    const float* w1r   = (const float*)d_in[1];
    const float* w1i   = (const float*)d_in[2];
    const float* w2r   = (const float*)d_in[3];
    const float* w2i   = (const float*)d_in[4];
    const float* pw_w  = (const float*)d_in[5];
    const float* pw_b  = (const float*)d_in[6];
    const float* fc0_w = (const float*)d_in[7];
    const float* fc0_b = (const float*)d_in[8];
    const float* fc1_w = (const float*)d_in[9];
    const float* fc1_b = (const float*)d_in[10];
    const float* fc2_w = (const float*)d_in[11];
    const float* fc2_b = (const float*)d_in[12];
    float* out = (float*)d_out;
    float* ws  = (float*)d_ws;

    // pick largest batch chunk CB that fits ws_size (19.4 MB per sample)
    const size_t per_sample_floats = 4849664;   // 4,194,304 + 524,288 + 65,536 + 65,536
    int CB = 16;
    while (CB > 1 && (size_t)CB * per_sample_floats * 4 > ws_size) CB >>= 1;

    float*  h  = ws;
    float*  T  = ws + (size_t)CB * 4194304;
    float2* T2 = (float2*)T;
    float2* X2 = (float2*)(T + (size_t)CB * 524288);
    float2* Y2 = (float2*)(T + (size_t)CB * 524288 + (size_t)CB * 65536);
    float2* G2 = T2;   // reuse: T dead once X2 produced; G written after mix

    for (int c0 = 0; c0 < 16; c0 += CB) {
        const float* xc = x + (size_t)c0 * 20 * HW_TOT;
        float* oc = out + (size_t)c0 * 20 * HW_TOT;

        // lift: (CB,20,HW) -> h (CB,64,HW)
        conv1x1_kernel<20, 64, 20>
            <<<dim3(256, CB), 256, 0, stream>>>(xc, fc0_w, fc0_b, h);

        for (int l = 0; l < 4; ++l) {
            dft1_kernel <<<CB * 64 * 256 / 8, 256, 0, stream>>>(h, T);
            dft2_kernel <<<CB * 64, 512, 0, stream>>>(T2, X2);
            mix_kernel  <<<CB * 64, 512, 0, stream>>>(X2, Y2, w1r, w1i, w2r, w2i, l);
            idft1_kernel<<<CB * 64 * 16, 256, 0, stream>>>(Y2, G2);
            pwcomb_kernel<<<CB * 256, 1024, 0, stream>>>(h, G2, pw_w, pw_b, l, (l < 3) ? 1 : 0);
        }

        proj_kernel<<<dim3(256, CB), 256, 0, stream>>>(h, fc1_w, fc1_b, fc2_w, fc2_b, oc);
    }
}

// Round 4
// 2737.956 us; speedup vs baseline: 12.0964x; 1.6071x over previous
//
#include <hip/hip_runtime.h>
#include <hip/hip_bf16.h>

// FNO2d: B=16, CIN=20, H=W=256, WIDTH=64, M1=M2=16, NLAYERS=4, FC_HID=128, COUT=20
// Round 3: R2 profile -> dft1 LDS-issue bound (2 ds_read per FMA, 1.6e8 bank conflicts,
// 479us x4). Rewrite dft1 as register-tiled GEMM (dfty): b128 LDS reads, 16 acc/thread,
// 8 b128 per 64 FMA. pwcomb: fold conv(K=64)+iDFT-y(K=32) into one K=96 GEMM with
// 4y x 4o thread tiles; lanes span y and o so LDS reads are partial-broadcast b128.
//
// Per-sample workspace (floats): h 4,194,304 | T/G 524,288 | X2 65,536 | Y2 65,536
// = 4,849,664 floats (19.4 MB); CB=16 -> 310 MB.

#define HW_TOT 65536
#define PI2_256 0.024543692606170259758f  // 2*pi/256

__device__ __forceinline__ float gelu_exact(float v) {
    return 0.5f * v * (1.0f + erff(v * 0.70710678118654752440f));
}
#define F4COMP(v, k) ((k)==0?(v).x:(k)==1?(v).y:(k)==2?(v).z:(v).w)

// ---------------- 1x1 conv (lift)
template<int CI, int CO, int WS>
__global__ void __launch_bounds__(256) conv1x1_kernel(
    const float* __restrict__ in, const float* __restrict__ w,
    const float* __restrict__ bias, float* __restrict__ out)
{
    const int b = blockIdx.y;
    const int p = blockIdx.x * 256 + threadIdx.x;
    const float* inp = in + (size_t)b * CI * HW_TOT + p;
    float acc[CO];
#pragma unroll
    for (int o = 0; o < CO; ++o) acc[o] = bias[o];
    for (int ci = 0; ci < CI; ++ci) {
        float hv = inp[(size_t)ci * HW_TOT];
#pragma unroll
        for (int o = 0; o < CO; ++o)
            acc[o] = fmaf(w[o * WS + ci], hv, acc[o]);
    }
    float* op = out + (size_t)b * CO * HW_TOT + p;
#pragma unroll
    for (int o = 0; o < CO; ++o) op[(size_t)o * HW_TOT] = acc[o];
}

// ---------------- forward DFT over y as GEMM: T[row*32 + 2ky+c] = sum_y h[row,y]*W[y][2ky+c]
// W[y][2ky] = cos(2pi y ky/256), W[y][2ky+1] = -sin(...). Block: 128 rows x 32 j, 256 thr.
// Thread: jg = t&7 (j = 4jg..+3), rg = t>>3 (rows rg+32k, k<4). 16 acc.
// Per 4-y: 4 As b128 (8 distinct addrs, disjoint bank quads via pad 68) + 4 Ws b128
// (8 distinct addrs at banks 4jg) -> conflict-free; 64 FMA.
__global__ void __launch_bounds__(256) dfty_kernel(
    const float* __restrict__ h, float* __restrict__ T)
{
    __shared__ float As[128][68];     // y-chunk of 64, padded
    __shared__ float Ws[256][32];     // twiddle table
    __shared__ float cs2[256], sn2[256];
    const int t = threadIdx.x;
    {
        float a = (float)t * PI2_256;
        cs2[t] = cosf(a); sn2[t] = sinf(a);
    }
    __syncthreads();
    for (int i = t; i < 8192; i += 256) {
        int y = i >> 5, j = i & 31, ky = j >> 1;
        int m = (y * ky) & 255;
        Ws[y][j] = (j & 1) ? -sn2[m] : cs2[m];
    }
    // (Ws writes complete before first loop barrier below)

    const size_t rowbase = (size_t)blockIdx.x * 128;
    const int jg = t & 7, rg = t >> 3;
    float acc[4][4];
#pragma unroll
    for (int k = 0; k < 4; ++k)
#pragma unroll
        for (int q = 0; q < 4; ++q) acc[k][q] = 0.0f;

    for (int yc = 0; yc < 256; yc += 64) {
        __syncthreads();   // protect As from previous iteration's readers
        // stage As[128][64]: 2048 float4; lane-consecutive = y-consecutive (coalesced)
#pragma unroll
        for (int it = 0; it < 8; ++it) {
            int idx = t + 256 * it;
            int rr = idx >> 4, c4 = idx & 15;
            float4 v = *(const float4*)(h + (rowbase + rr) * 256 + yc + c4 * 4);
            *(float4*)&As[rr][c4 * 4] = v;
        }
        __syncthreads();
#pragma unroll 2
        for (int yy = 0; yy < 64; yy += 4) {
            float4 wv[4], av[4];
#pragma unroll
            for (int q = 0; q < 4; ++q) wv[q] = *(const float4*)&Ws[yc + yy + q][jg * 4];
#pragma unroll
            for (int k = 0; k < 4; ++k) av[k] = *(const float4*)&As[rg + 32 * k][yy];
#pragma unroll
            for (int k = 0; k < 4; ++k)
#pragma unroll
                for (int q = 0; q < 4; ++q) {
                    float a = F4COMP(av[k], q);
                    acc[k][0] = fmaf(a, wv[q].x, acc[k][0]);
                    acc[k][1] = fmaf(a, wv[q].y, acc[k][1]);
                    acc[k][2] = fmaf(a, wv[q].z, acc[k][2]);
                    acc[k][3] = fmaf(a, wv[q].w, acc[k][3]);
                }
        }
    }
#pragma unroll
    for (int k = 0; k < 4; ++k) {
        float4 v = make_float4(acc[k][0], acc[k][1], acc[k][2], acc[k][3]);
        *(float4*)&T[(rowbase + rg + 32 * k) * 32 + jg * 4] = v;
    }
}

// ---------------- forward DFT over x: X[bc,kxi,ky] = sum_x T[bc,x,ky] * e^{-2pi i kx x/256}
__global__ void __launch_bounds__(512) dft2_kernel(
    const float2* __restrict__ T2, float2* __restrict__ X2)
{
    __shared__ float cs[256], sn[256];
    const int t = threadIdx.x;
    if (t < 256) {
        float a = (float)t * PI2_256;
        cs[t] = cosf(a); sn[t] = sinf(a);
    }
    __syncthreads();
    const int bc = blockIdx.x;
    const int ky = t & 15, kxi = t >> 4;
    const int kx = (kxi < 16) ? kxi : (224 + kxi);
    const float2* Tp = T2 + (size_t)bc * 4096 + ky;
    float xr = 0.0f, xi = 0.0f;
    int m = 0;
    for (int x = 0; x < 256; ++x) {
        float2 tv = Tp[(size_t)x * 16];
        float c = cs[m], s = sn[m];
        xr = fmaf(tv.x, c, fmaf(tv.y, s, xr));
        xi = fmaf(tv.y, c, fmaf(-tv.x, s, xi));
        m = (m + kx) & 255;
    }
    X2[(size_t)bc * 512 + t] = make_float2(xr, xi);
}

// ---------------- complex mode mixing
__global__ void __launch_bounds__(512) mix_kernel(
    const float2* __restrict__ X2, float2* __restrict__ Y2,
    const float* __restrict__ w1r, const float* __restrict__ w1i,
    const float* __restrict__ w2r, const float* __restrict__ w2i, int layer)
{
    const int bo = blockIdx.x;
    const int b = bo >> 6, o = bo & 63;
    const int t = threadIdx.x;
    const int ky = t & 15, kxi = t >> 4;
    const bool top = (kxi < 16);
    const int kxm = top ? kxi : (kxi - 16);
    const float* wr = top ? w1r : w2r;
    const float* wi = top ? w1i : w2i;
    float yr = 0.0f, yi = 0.0f;
    for (int i = 0; i < 64; ++i) {
        float2 xv = X2[((size_t)(b * 64 + i) * 32 + kxi) * 16 + ky];
        size_t widx = (((size_t)layer * 64 + i) * 64 + o) * 256 + (kxm * 16 + ky);
        float wrv = wr[widx], wiv = wi[widx];
        yr = fmaf(xv.x, wrv, fmaf(-xv.y, wiv, yr));
        yi = fmaf(xv.x, wiv, fmaf(xv.y, wrv, yi));
    }
    Y2[((size_t)(b * 64 + o) * 32 + kxi) * 16 + ky] = make_float2(yr, yi);
}

// ---------------- inverse DFT over x
__global__ void __launch_bounds__(256) idft1_kernel(
    const float2* __restrict__ Y2, float2* __restrict__ G2)
{
    __shared__ float cs[256], sn[256];
    const int t = threadIdx.x;
    {
        float a = (float)t * PI2_256;
        cs[t] = cosf(a); sn[t] = sinf(a);
    }
    __syncthreads();
    const int bo = blockIdx.x >> 4;
    const int xc = blockIdx.x & 15;
    const int ky = t & 15, xo = t >> 4;
    const int x = xc * 16 + xo;
    const float2* Yp = Y2 + (size_t)bo * 512 + ky;
    float gr = 0.0f, gi = 0.0f;
    for (int kxi = 0; kxi < 32; ++kxi) {
        float2 yv = Yp[(size_t)kxi * 16];
        int kx = (kxi < 16) ? kxi : (224 + kxi);
        int m = (kx * x) & 255;
        float c = cs[m], s = sn[m];
        gr = fmaf(yv.x, c, fmaf(-yv.y, s, gr));
        gi = fmaf(yv.x, s, fmaf(yv.y, c, gi));
    }
    G2[((size_t)bo * 256 + x) * 16 + ky] = make_float2(gr, gi);
}

// ---------------- fused pointwise conv + iDFT-y + add + GELU, in place on h.
// Round-3 rewrite: single K=96 GEMM per block (ci-part K=64 from hs/Wt, spectral
// K=32 from Gt/Pt). 1024 thr; thread: og = t&15 (o = 4og..+3), yg = t>>4 (y = 4yg..+3).
// Per K-step: 2 partial-broadcast b128 (4 and 16 distinct addrs) per 16 FMA.
__global__ void __launch_bounds__(1024) pwcomb_kernel(
    float* __restrict__ h, const float2* __restrict__ G2,
    const float* __restrict__ pw_w, const float* __restrict__ pw_b,
    int layer, int do_gelu)
{
    __shared__ float hs[64][256];     // [ci][y] 64 KB
    __shared__ float Wt[64][65];      // [ci][o] transposed, padded (16.6 KB)
    __shared__ float Gt[32][64];      // [j'][o] 8 KB
    __shared__ float Pt[32][256];     // [j'][y] 32 KB
    __shared__ float cs[256], sn[256];
    const int t = threadIdx.x;
    const int b = blockIdx.x >> 8;
    const int x = blockIdx.x & 255;
    if (t < 256) {
        float a = (float)t * PI2_256;
        cs[t] = cosf(a); sn[t] = sinf(a);
    }
    __syncthreads();

    // Wt[ci][o] from pw_w[layer][o][ci]
    const float* wl = pw_w + layer * 4096;
    for (int i = t; i < 4096; i += 1024) { int o = i >> 6, ci = i & 63; Wt[ci][o] = wl[i]; }
    // Gt from G2
    {
        int o = t >> 4, ky = t & 15;
        float2 g = G2[((size_t)(b * 64 + o) * 256 + x) * 16 + ky];
        Gt[2 * ky][o] = g.x;
        Gt[2 * ky + 1][o] = g.y;
    }
    // Pt[j'][y]: j'=2ky -> wk*cos(2pi ky y/256); j'=2ky+1 -> -wk*sin(...)
    const float inv = 1.0f / 65536.0f;
#pragma unroll
    for (int it = 0; it < 8; ++it) {
        int i = t + 1024 * it;
        int jp = i >> 8, y = i & 255, ky = jp >> 1;
        int m = (ky * y) & 255;
        float wk = (ky == 0) ? inv : 2.0f * inv;
        Pt[jp][y] = (jp & 1) ? -wk * sn[m] : wk * cs[m];
    }
    // stage hs (all reads of h precede the barrier; writes after -> in-place safe)
#pragma unroll
    for (int it = 0; it < 4; ++it) {
        int idx = t + 1024 * it;
        int ci = idx >> 6, c4 = idx & 63;
        float4 v = *(const float4*)(h + ((size_t)(b * 64 + ci) * 256 + x) * 256 + c4 * 4);
        *(float4*)&hs[ci][c4 * 4] = v;
    }
    __syncthreads();

    const int og = t & 15, yg = t >> 4;
    const float* bl = pw_b + layer * 64;
    float acc[4][4];   // [yj][oj]
#pragma unroll
    for (int oj = 0; oj < 4; ++oj) {
        float bv = bl[og * 4 + oj];
#pragma unroll
        for (int yj = 0; yj < 4; ++yj) acc[yj][oj] = bv;
    }
    // conv part: K = 64
    for (int ci = 0; ci < 64; ++ci) {
        float4 hv = *(const float4*)&hs[ci][yg * 4];
        float4 wv = *(const float4*)&Wt[ci][og * 4];
#pragma unroll
        for (int yj = 0; yj < 4; ++yj) {
            float a = F4COMP(hv, yj);
            acc[yj][0] = fmaf(a, wv.x, acc[yj][0]);
            acc[yj][1] = fmaf(a, wv.y, acc[yj][1]);
            acc[yj][2] = fmaf(a, wv.z, acc[yj][2]);
            acc[yj][3] = fmaf(a, wv.w, acc[yj][3]);
        }
    }
    // spectral part: K = 32
#pragma unroll 4
    for (int jp = 0; jp < 32; ++jp) {
        float4 pv = *(const float4*)&Pt[jp][yg * 4];
        float4 gv = *(const float4*)&Gt[jp][og * 4];
#pragma unroll
        for (int yj = 0; yj < 4; ++yj) {
            float a = F4COMP(pv, yj);
            acc[yj][0] = fmaf(a, gv.x, acc[yj][0]);
            acc[yj][1] = fmaf(a, gv.y, acc[yj][1]);
            acc[yj][2] = fmaf(a, gv.z, acc[yj][2]);
            acc[yj][3] = fmaf(a, gv.w, acc[yj][3]);
        }
    }
    // epilogue: gelu + store (float4 per o-row)
#pragma unroll
    for (int oj = 0; oj < 4; ++oj) {
        float4 v;
        v.x = acc[0][oj]; v.y = acc[1][oj]; v.z = acc[2][oj]; v.w = acc[3][oj];
        if (do_gelu) {
            v.x = gelu_exact(v.x); v.y = gelu_exact(v.y);
            v.z = gelu_exact(v.z); v.w = gelu_exact(v.w);
        }
        *(float4*)&h[((size_t)(b * 64 + og * 4 + oj) * 256 + x) * 256 + yg * 4] = v;
    }
}

// ---------------- fused projection: out = fc2(gelu(fc1(h))) per pixel.
__global__ void __launch_bounds__(256) proj_kernel(
    const float* __restrict__ h,
    const float* __restrict__ w1, const float* __restrict__ b1,
    const float* __restrict__ w2, const float* __restrict__ b2,
    float* __restrict__ out)
{
    const int b = blockIdx.y;
    const int p = blockIdx.x * 256 + threadIdx.x;
    const float* hp = h + (size_t)b * 64 * HW_TOT + p;
    float hreg[64];
#pragma unroll
    for (int ci = 0; ci < 64; ++ci) hreg[ci] = hp[(size_t)ci * HW_TOT];
    float acc[20];
#pragma unroll
    for (int o = 0; o < 20; ++o) acc[o] = b2[o];
    for (int hd = 0; hd < 128; ++hd) {
        float v = b1[hd];
        const float* wr = w1 + hd * 64;
#pragma unroll
        for (int ci = 0; ci < 64; ++ci) v = fmaf(wr[ci], hreg[ci], v);
        v = gelu_exact(v);
#pragma unroll
        for (int o = 0; o < 20; ++o) acc[o] = fmaf(w2[o * 128 + hd], v, acc[o]);
    }
    float* op = out + (size_t)b * 20 * HW_TOT + p;
#pragma unroll
    for (int o = 0; o < 20; ++o) op[(size_t)o * HW_TOT] = acc[o];
}

extern "C" void kernel_launch(void* const* d_in, const int* in_sizes, int n_in,
                              void* d_out, int out_size, void* d_ws, size_t ws_size,
                              hipStream_t stream)
{
    const float* x     = (const float*)d_in[0];
    const float* w1r   = (const float*)d_in[1];
    const float* w1i   = (const float*)d_in[2];
    const float* w2r   = (const float*)d_in[3];
    const float* w2i   = (const float*)d_in[4];
    const float* pw_w  = (const float*)d_in[5];
    const float* pw_b  = (const float*)d_in[6];
    const float* fc0_w = (const float*)d_in[7];
    const float* fc0_b = (const float*)d_in[8];
    const float* fc1_w = (const float*)d_in[9];
    const float* fc1_b = (const float*)d_in[10];
    const float* fc2_w = (const float*)d_in[11];
    const float* fc2_b = (const float*)d_in[12];
    float* out = (float*)d_out;
    float* ws  = (float*)d_ws;

    const size_t per_sample_floats = 4849664;
    int CB = 16;
    while (CB > 1 && (size_t)CB * per_sample_floats * 4 > ws_size) CB >>= 1;

    float*  h  = ws;
    float*  T  = ws + (size_t)CB * 4194304;
    float2* T2 = (float2*)T;
    float2* X2 = (float2*)(T + (size_t)CB * 524288);
    float2* Y2 = (float2*)(T + (size_t)CB * 524288 + (size_t)CB * 65536);
    float2* G2 = T2;   // reuse

    for (int c0 = 0; c0 < 16; c0 += CB) {
        const float* xc = x + (size_t)c0 * 20 * HW_TOT;
        float* oc = out + (size_t)c0 * 20 * HW_TOT;

        conv1x1_kernel<20, 64, 20>
            <<<dim3(256, CB), 256, 0, stream>>>(xc, fc0_w, fc0_b, h);

        for (int l = 0; l < 4; ++l) {
            dfty_kernel <<<CB * 128, 256, 0, stream>>>(h, T);
            dft2_kernel <<<CB * 64, 512, 0, stream>>>(T2, X2);
            mix_kernel  <<<CB * 64, 512, 0, stream>>>(X2, Y2, w1r, w1i, w2r, w2i, l);
            idft1_kernel<<<CB * 64 * 16, 256, 0, stream>>>(Y2, G2);
            pwcomb_kernel<<<CB * 256, 1024, 0, stream>>>(h, G2, pw_w, pw_b, l, (l < 3) ? 1 : 0);
        }

        proj_kernel<<<dim3(256, CB), 256, 0, stream>>>(h, fc1_w, fc1_b, fc2_w, fc2_b, oc);
    }
}